// Round 9
// baseline (262.106 us; speedup 1.0000x reference)
//
#include <hip/hip_runtime.h>
#include <math.h>

#define NENT 50000
#define RREL 2000
#define AATT 5000
#define EE   400000
#define E2   800000
#define EAE  400000
#define PB   2048   // partials stride per head

__device__ __forceinline__ float leaky(float v){ return v > 0.f ? v : 0.3f * v; }

__device__ __forceinline__ float wave_sum(float v){
#pragma unroll
  for (int m = 32; m; m >>= 1) v += __shfl_xor(v, m);
  return v;
}
__device__ __forceinline__ float sum16(float v){
#pragma unroll
  for (int m = 1; m < 16; m <<= 1) v += __shfl_xor(v, m);
  return v;
}
__device__ __forceinline__ float sum8(float v){
#pragma unroll
  for (int m = 1; m < 8; m <<= 1) v += __shfl_xor(v, m);
  return v;
}

// bf16 pair pack/unpack (round-to-nearest-even); low half = even dim
__device__ __forceinline__ unsigned pack2(float a, float b){
  unsigned ua = __float_as_uint(a); ua += 0x7FFFu + ((ua >> 16) & 1u);
  unsigned ub = __float_as_uint(b); ub += 0x7FFFu + ((ub >> 16) & 1u);
  return (ua >> 16) | (ub & 0xFFFF0000u);
}
__device__ __forceinline__ float2 unpack2(unsigned u){
  float2 r;
  r.x = __uint_as_float(u << 16);
  r.y = __uint_as_float(u & 0xFFFF0000u);
  return r;
}

__device__ int lowb(const int* a, int n, int key){
  int lo = 0, hi = n;
  while (lo < hi){ int mid = (lo + hi) >> 1; if (a[2 * mid] < key) lo = mid + 1; else hi = mid; }
  return lo;
}

__global__ void k_ptr(const int* ee, const int* er, const int* ea,
                      int* pee, int* per, int* pea){
  int i = blockIdx.x * blockDim.x + threadIdx.x;
  if (i > NENT) return;
  pee[i] = lowb(ee, EE, i);
  per[i] = lowb(er, E2, i);
  pea[i] = lowb(ea, EAE, i);
}

// per-relation/attr scalar tables + bf16 copies; HH_l[r]=(hr_h0,hr_h1,hc_h0,hc_h1)
__global__ void k_small(const float* rel_emb, const float* attr_emb,
                        const float* w_r, const float* w_a,
                        const float* eaw, const float* caw,
                        float* h_rel, float* h_attr, float4* HH0, float4* HH1,
                        unsigned* rel16, unsigned* attr16){
  int t = blockIdx.x * blockDim.x + threadIdx.x;
  if (t < RREL){
    const float* e = rel_emb + (size_t)t * 64;
    float s = 0.f;
    for (int k = 0; k < 64; ++k) s += e[k] * w_r[128 + k];
    h_rel[t] = s;
    float hr[4], hc[4];
    for (int lh = 0; lh < 4; ++lh){
      float a = 0.f, c = 0.f;
      for (int k = 0; k < 64; ++k){
        a += e[k] * eaw[lh * 192 + 64 + k];
        c += e[k] * caw[lh * 320 + 128 + k];
      }
      hr[lh] = a; hc[lh] = c;
    }
    HH0[t] = make_float4(hr[0], hr[1], hc[0], hc[1]);
    HH1[t] = make_float4(hr[2], hr[3], hc[2], hc[3]);
    for (int k = 0; k < 32; ++k) rel16[t * 32 + k] = pack2(e[2 * k], e[2 * k + 1]);
  }
  if (t < AATT){
    const float* e = attr_emb + (size_t)t * 64;
    float s = 0.f;
    for (int k = 0; k < 64; ++k) s += e[k] * w_a[128 + k];
    h_attr[t] = s;
    for (int k = 0; k < 32; ++k) attr16[t * 32 + k] = pack2(e[2 * k], e[2 * k + 1]);
  }
}

// wave per entity: her/hea dot tables + bf16 copy of ent_emb (one read pass)
__global__ void k_e16(const float* ent_emb, const float* w_r, const float* w_a,
                      float* her, float* hea, unsigned* ent16){
  int w = (blockIdx.x * blockDim.x + threadIdx.x) >> 6;
  int lane = threadIdx.x & 63;
  if (w >= NENT) return;
  float2 v = ((const float2*)(ent_emb + (size_t)w * 128))[lane];
  float2 a = ((const float2*)w_r)[lane];
  float2 b = ((const float2*)w_a)[lane];
  float sr = wave_sum(v.x * a.x + v.y * a.y);
  float sa = wave_sum(v.x * b.x + v.y * b.y);
  ent16[(size_t)w * 64 + lane] = pack2(v.x, v.y);
  if (lane == 0){ her[w] = sr; hea[w] = sa; }
}

// edge-parallel concept-attention weights for BOTH lists
__global__ void k_cw(const int* er_idx, const int* ea_idx,
                     const float* her, const float* hea,
                     const float* h_rel, const float* h_attr,
                     const float* b_r, const float* b_a,
                     float* wr, float* wa){
  int e = blockIdx.x * blockDim.x + threadIdx.x;
  if (e < E2){
    int2 rc = ((const int2*)er_idx)[e];
    wr[e] = __expf(leaky(her[rc.x] + h_rel[rc.y] + b_r[0]));
  }
  if (e < EAE){
    int2 rc = ((const int2*)ea_idx)[e];
    wa[e] = __expf(leaky(hea[rc.x] + h_attr[rc.y] + b_a[0]));
  }
}

// concept aggregation, 16-lane group per entity, bf16 rows (128 B), unroll-8.
// lane p owns dims [4p,4p+4).
__device__ float4 concept_g(const float* wq, const int* idx, int beg, int end,
                            const unsigned* emb16, int p){
  float t = 0.f;
  for (int e = beg + p; e < end; e += 16) t += wq[e];
  t = sum16(t);
  float invz = (t > 0.f) ? (1.f / t) : 0.f;
  float4 acc = {0.f, 0.f, 0.f, 0.f};
  for (int c0 = beg; c0 < end; c0 += 8){
    int cnt = end - c0; if (cnt > 8) cnt = 8;
#pragma unroll
    for (int j = 0; j < 8; ++j){
      int e = c0 + ((j < cnt) ? j : 0);
      float wgt = (j < cnt) ? wq[e] * invz : 0.f;
      int obj = ((const int2*)idx)[e].y;
      uint2 q = ((const uint2*)(emb16 + (size_t)obj * 32))[p];
      float2 f0 = unpack2(q.x), f1 = unpack2(q.y);
      acc.x = fmaf(wgt, f0.x, acc.x); acc.y = fmaf(wgt, f0.y, acc.y);
      acc.z = fmaf(wgt, f1.x, acc.z); acc.w = fmaf(wgt, f1.y, acc.w);
    }
  }
  acc.x = fmaxf(acc.x, 0.f); acc.y = fmaxf(acc.y, 0.f);
  acc.z = fmaxf(acc.z, 0.f); acc.w = fmaxf(acc.w, 0.f);
  return acc;
}

// row-local per-entity work, 16-lane group per entity: both concept GATs,
// bf16 mean aggregation -> x16a (relu'd, bf16, no f32 x0), A/B tables, uv0.
__global__ void k_phase1(const unsigned* ent16, const unsigned* rel16, const unsigned* attr16,
                         const float* eaw, const float* caw,
                         const int* er_idx, const int* ea_idx, const int* ee,
                         const int* per, const int* pea, const int* pee,
                         const float* wr, const float* wa,
                         float4* UA0, float4* VB0, float4* UA1, float4* VB1,
                         float* out, unsigned* x16a){
  int tid = blockIdx.x * blockDim.x + threadIdx.x;
  int lane = threadIdx.x & 63;
  int p = lane & 15;
  int w = (tid >> 6) * 4 + (lane >> 4);
  if (w >= NENT) return;
  // concept aggregations (lane p owns dims [4p,4p+4))
  float4 accR = concept_g(wr, er_idx, per[w], per[w + 1], rel16, p);
  float4 accA = concept_g(wa, ea_idx, pea[w], pea[w + 1], attr16, p);
  ((float4*)(out + (size_t)w * 384 + 256))[p] = accR;
  ((float4*)(out + (size_t)w * 384 + 320))[p] = accA;
  ((float4*)(out + (size_t)NENT * 384 + (size_t)w * 128))[p] = accR;
  ((float4*)(out + (size_t)NENT * 384 + (size_t)w * 128 + 64))[p] = accA;
  // mean neighbor aggregation from bf16 rows (256 B), unroll-8
  int beg = pee[w], end = pee[w + 1];
  float4 mx = {0.f,0.f,0.f,0.f}, my = {0.f,0.f,0.f,0.f};
  for (int c0 = beg; c0 < end; c0 += 8){
    int cnt = end - c0; if (cnt > 8) cnt = 8;
#pragma unroll
    for (int j = 0; j < 8; ++j){
      int e = c0 + ((j < cnt) ? j : 0);
      float msk = (j < cnt) ? 1.f : 0.f;
      int ce = ((const int2*)ee)[e].y;
      uint4 q = ((const uint4*)(ent16 + (size_t)ce * 64))[p];
      float2 d0 = unpack2(q.x), d1 = unpack2(q.y), d2 = unpack2(q.z), d3 = unpack2(q.w);
      mx.x = fmaf(msk, d0.x, mx.x); mx.y = fmaf(msk, d0.y, mx.y);
      mx.z = fmaf(msk, d1.x, mx.z); mx.w = fmaf(msk, d1.y, mx.w);
      my.x = fmaf(msk, d2.x, my.x); my.y = fmaf(msk, d2.y, my.y);
      my.z = fmaf(msk, d3.x, my.z); my.w = fmaf(msk, d3.y, my.w);
    }
  }
  float invd = 1.f / fmaxf((float)(end - beg), 1.f);
  // relu(x0) dims [8p,8p+8)
  float e0 = fmaxf(mx.x * invd, 0.f), e1 = fmaxf(mx.y * invd, 0.f);
  float e2 = fmaxf(mx.z * invd, 0.f), e3 = fmaxf(mx.w * invd, 0.f);
  float e4 = fmaxf(my.x * invd, 0.f), e5 = fmaxf(my.y * invd, 0.f);
  float e6 = fmaxf(my.z * invd, 0.f), e7 = fmaxf(my.w * invd, 0.f);
  uint4 s; s.x = pack2(e0, e1); s.y = pack2(e2, e3); s.z = pack2(e4, e5); s.w = pack2(e6, e7);
  ((uint4*)(x16a + (size_t)w * 64))[p] = s;
  // con-attention tables A (row) / B (col) for all 4 (l,h)
#pragma unroll
  for (int lh = 0; lh < 4; ++lh){
    const float* cw = caw + lh * 320;
    float4 c0 = *(const float4*)(cw + 4 * p);
    float4 c1 = *(const float4*)(cw + 64 + 4 * p);
    float4 c2 = *(const float4*)(cw + 192 + 4 * p);
    float4 c3 = *(const float4*)(cw + 256 + 4 * p);
    float av = accR.x*c0.x + accR.y*c0.y + accR.z*c0.z + accR.w*c0.w
             + accA.x*c1.x + accA.y*c1.y + accA.z*c1.z + accA.w*c1.w;
    float bv = accR.x*c2.x + accR.y*c2.y + accR.z*c2.z + accR.w*c2.w
             + accA.x*c3.x + accA.y*c3.y + accA.z*c3.z + accA.w*c3.w;
    av = sum16(av); bv = sum16(bv);
    if (p == 0){
      float4* U = (lh < 2) ? UA0 : UA1;
      float4* V = (lh < 2) ? VB0 : VB1;
      ((float*)(U + w))[2 + (lh & 1)] = av;
      ((float*)(V + w))[2 + (lh & 1)] = bv;
    }
  }
  // layer-0 u/v: lane p owns dims [8p,8p+8); p<8 head0, p>=8 head1
  {
    int hh = p >> 3;
    int dbase = (8 * p) & 63;
    const float* wvp = eaw + hh * 192;
    float4 u0 = *(const float4*)(wvp + dbase);
    float4 u1 = *(const float4*)(wvp + dbase + 4);
    float4 q0 = *(const float4*)(wvp + 128 + dbase);
    float4 q1 = *(const float4*)(wvp + 128 + dbase + 4);
    float pu = e0*u0.x + e1*u0.y + e2*u0.z + e3*u0.w
             + e4*u1.x + e5*u1.y + e6*u1.z + e7*u1.w;
    float pv = e0*q0.x + e1*q0.y + e2*q0.z + e3*q0.w
             + e4*q1.x + e5*q1.y + e6*q1.z + e7*q1.w;
    pu = sum8(pu); pv = sum8(pv);
    if (p == 0 || p == 8){
      ((float*)(UA0 + w))[hh] = pu;
      ((float*)(VB0 + w))[hh] = pv;
    }
  }
}

// fused edge scores + exp (no global max) + block sums; s01[e] = {ex0, ex1}
__global__ void k_se(const int* ee, const int* err,
                     const float4* UA, const float4* VB, const float4* HH,
                     const float* eab_l, const float* cab_l,
                     float2* s01, float* partials){
  int e = blockIdx.x * blockDim.x + threadIdx.x;
  int tid = threadIdx.x;
  __shared__ float sm0[4], sm1[4];
  float ex0 = 0.f, ex1 = 0.f;
  if (e < EE){
    int2 rc = ((const int2*)ee)[e];
    int2 rr = ((const int2*)err)[e];
    float4 ua = UA[rc.x], vb = VB[rc.y], h1 = HH[rr.x], h2 = HH[rr.y];
    float ea0 = ua.x + 0.5f * (h1.x + h2.x) + vb.x + eab_l[0];
    float ca0 = ua.z + 0.5f * (h1.z + h2.z) + vb.z + cab_l[0];
    ex0 = __expf(leaky(ea0) * leaky(ca0));
    float ea1 = ua.y + 0.5f * (h1.y + h2.y) + vb.y + eab_l[1];
    float ca1 = ua.w + 0.5f * (h1.w + h2.w) + vb.w + cab_l[1];
    ex1 = __expf(leaky(ea1) * leaky(ca1));
    s01[e] = make_float2(ex0, ex1);
  }
  float b0 = wave_sum(ex0), b1 = wave_sum(ex1);
  if ((tid & 63) == 0){ sm0[tid >> 6] = b0; sm1[tid >> 6] = b1; }
  __syncthreads();
  if (tid == 0)  partials[blockIdx.x]      = sm0[0] + sm0[1] + sm0[2] + sm0[3];
  if (tid == 64) partials[PB + blockIdx.x] = sm1[0] + sm1[1] + sm1[2] + sm1[3];
}

// single-block finalize: Z per head
__global__ void k_final(const float* partials, float* scal, int nb){
  __shared__ float sm[1024];
  int tid = threadIdx.x;
  for (int h = 0; h < 2; ++h){
    float v = 0.f;
    for (int i = tid; i < nb; i += 1024) v += partials[h * PB + i];
    sm[tid] = v; __syncthreads();
    for (int s = 512; s; s >>= 1){
      if (tid < s) sm[tid] += sm[tid + s];
      __syncthreads();
    }
    if (tid == 0) scal[h] = sm[0];
    __syncthreads();
  }
}

// edge-parallel: q = exp(s/Z) in place
__global__ void k_q(float2* s01, const float* scal){
  int e = blockIdx.x * blockDim.x + threadIdx.x;
  if (e >= EE) return;
  float invZ0 = 1.f / scal[0], invZ1 = 1.f / scal[1];
  float2 s = s01[e];
  s01[e] = make_float2(__expf(s.x * invZ0), __expf(s.y * invZ1));
}

// segment softmax (seg-sum of q) + PV gather from bf16 relu'd rows (256 B),
// unroll-8. lane p owns dims [8p,8p+8); p<8 head0, p>=8 head1. Writes f32
// tanh out; optionally bf16 relu(tanh) for next layer + fused next-layer u/v.
__global__ void k_agg(const int* ee, const int* ptr, const float2* q01,
                      const unsigned* x16src, float* outp, int ocol,
                      const float* eaw_next, float4* UAn, float4* VBn,
                      unsigned* x16dst){
  int tid = blockIdx.x * blockDim.x + threadIdx.x;
  int lane = threadIdx.x & 63;
  int p = lane & 15;
  int w = (tid >> 6) * 4 + (lane >> 4);
  if (w >= NENT) return;
  int beg = ptr[w], end = ptr[w + 1];
  float t0 = 0.f, t1 = 0.f;
  for (int e = beg + p; e < end; e += 16){
    float2 q = q01[e];
    t0 += q.x; t1 += q.y;
  }
  t0 = sum16(t0); t1 = sum16(t1);
  float iz0 = (t0 > 0.f) ? (1.f / t0) : 0.f;
  float iz1 = (t1 > 0.f) ? (1.f / t1) : 0.f;
  float izs = (p < 8) ? iz0 : iz1;
  float4 a0 = {0.f,0.f,0.f,0.f}, a1 = {0.f,0.f,0.f,0.f};
  for (int c0 = beg; c0 < end; c0 += 8){
    int cnt = end - c0; if (cnt > 8) cnt = 8;
#pragma unroll
    for (int j = 0; j < 8; ++j){
      int e = c0 + ((j < cnt) ? j : 0);
      float2 q = q01[e];
      float ws = (j < cnt) ? ((p < 8) ? q.x : q.y) * izs : 0.f;
      int cj = ((const int2*)ee)[e].y;
      uint4 r = ((const uint4*)(x16src + (size_t)cj * 64))[p];
      float2 d0 = unpack2(r.x), d1 = unpack2(r.y), d2 = unpack2(r.z), d3 = unpack2(r.w);
      a0.x = fmaf(ws, d0.x, a0.x); a0.y = fmaf(ws, d0.y, a0.y);
      a0.z = fmaf(ws, d1.x, a0.z); a0.w = fmaf(ws, d1.y, a0.w);
      a1.x = fmaf(ws, d2.x, a1.x); a1.y = fmaf(ws, d2.y, a1.y);
      a1.z = fmaf(ws, d3.x, a1.z); a1.w = fmaf(ws, d3.y, a1.w);
    }
  }
  float4 o0, o1;
  o0.x = tanhf(a0.x); o0.y = tanhf(a0.y); o0.z = tanhf(a0.z); o0.w = tanhf(a0.w);
  o1.x = tanhf(a1.x); o1.y = tanhf(a1.y); o1.z = tanhf(a1.z); o1.w = tanhf(a1.w);
  ((float4*)(outp + (size_t)w * 384 + ocol))[2 * p]     = o0;
  ((float4*)(outp + (size_t)w * 384 + ocol))[2 * p + 1] = o1;
  if (x16dst){
    float e0 = fmaxf(o0.x,0.f), e1 = fmaxf(o0.y,0.f), e2 = fmaxf(o0.z,0.f), e3 = fmaxf(o0.w,0.f);
    float e4 = fmaxf(o1.x,0.f), e5 = fmaxf(o1.y,0.f), e6 = fmaxf(o1.z,0.f), e7 = fmaxf(o1.w,0.f);
    uint4 s; s.x = pack2(e0, e1); s.y = pack2(e2, e3); s.z = pack2(e4, e5); s.w = pack2(e6, e7);
    ((uint4*)(x16dst + (size_t)w * 64))[p] = s;
    int hh = p >> 3;
    int dbase = (8 * p) & 63;
    const float* wvp = eaw_next + hh * 192;
    float4 u0 = *(const float4*)(wvp + dbase);
    float4 u1 = *(const float4*)(wvp + dbase + 4);
    float4 q0 = *(const float4*)(wvp + 128 + dbase);
    float4 q1 = *(const float4*)(wvp + 128 + dbase + 4);
    float pu = e0*u0.x + e1*u0.y + e2*u0.z + e3*u0.w
             + e4*u1.x + e5*u1.y + e6*u1.z + e7*u1.w;
    float pv = e0*q0.x + e1*q0.y + e2*q0.z + e3*q0.w
             + e4*q1.x + e5*q1.y + e6*q1.z + e7*q1.w;
    pu = sum8(pu); pv = sum8(pv);
    if (p == 0 || p == 8){
      ((float*)(UAn + w))[hh] = pu;
      ((float*)(VBn + w))[hh] = pv;
    }
  }
}

extern "C" void kernel_launch(void* const* d_in, const int* in_sizes, int n_in,
                              void* d_out, int out_size, void* d_ws, size_t ws_size,
                              hipStream_t stream){
  const float* ent_emb  = (const float*)d_in[0];
  const float* rel_emb  = (const float*)d_in[1];
  const float* attr_emb = (const float*)d_in[2];
  const float* w_r      = (const float*)d_in[3];
  const float* b_r      = (const float*)d_in[4];
  const float* w_a      = (const float*)d_in[5];
  const float* b_a      = (const float*)d_in[6];
  const float* eaw      = (const float*)d_in[7];
  const float* eab      = (const float*)d_in[8];
  const float* caw      = (const float*)d_in[9];
  const float* cab      = (const float*)d_in[10];
  const int*   ee       = (const int*)d_in[11];
  const int*   er_rel2  = (const int*)d_in[13];  // per-ee-edge relation pair (E2)
  const int*   er_idx   = (const int*)d_in[14];
  const int*   ea_idx   = (const int*)d_in[15];
  float* out = (float*)d_out;

  // workspace carve (~36 MB)
  int* pee = (int*)d_ws;                 // NENT+1
  int* per = pee + (NENT + 1);
  int* pea = per + (NENT + 1);
  float*  fbase = (float*)d_ws + 150004; // 16B-aligned
  float4* UA0 = (float4*)fbase;          // NENT each
  float4* VB0 = UA0 + NENT;
  float4* UA1 = VB0 + NENT;
  float4* VB1 = UA1 + NENT;
  float4* HH0 = VB1 + NENT;              // RREL each
  float4* HH1 = HH0 + RREL;
  float* her     = (float*)(HH1 + RREL); // NENT
  float* hea     = her + NENT;           // NENT
  float* h_rel   = hea + NENT;           // RREL
  float* h_attr  = h_rel + RREL;         // AATT
  float* partials= h_attr + AATT;        // 2*PB
  float* scal    = partials + 2 * PB;    // 4
  float* wr      = scal + 4;             // E2 floats; ALIASED with s01 (EE float2)
  float* wa      = wr + E2;              // EAE floats
  float2* s01    = (float2*)wr;          // wr dead after k_phase1
  unsigned* rel16  = (unsigned*)(wa + EAE);       // RREL*32
  unsigned* attr16 = rel16 + RREL * 32;           // AATT*32
  unsigned* ent16  = attr16 + AATT * 32;          // NENT*64; dead after k_phase1
  unsigned* x16b   = ent16;                       // ALIAS: layer-0 out (bf16 relu)
  unsigned* x16a   = ent16 + (size_t)NENT * 64;   // NENT*64: relu(x0) bf16

  const int nb = (EE + 255) / 256;       // 1563 edge blocks
  const int gq = (NENT + 15) / 16;       // group-per-entity grids (16 ent/block)
  const int gw = (NENT + 3) / 4;         // wave-per-entity grids

  k_ptr<<<(NENT + 1 + 255) / 256, 256, 0, stream>>>(ee, er_idx, ea_idx, pee, per, pea);
  k_small<<<(AATT + 255) / 256, 256, 0, stream>>>(rel_emb, attr_emb, w_r, w_a, eaw, caw,
                                                  h_rel, h_attr, HH0, HH1, rel16, attr16);
  k_e16<<<gw, 256, 0, stream>>>(ent_emb, w_r, w_a, her, hea, ent16);
  k_cw<<<(E2 + 255) / 256, 256, 0, stream>>>(er_idx, ea_idx, her, hea,
                                             h_rel, h_attr, b_r, b_a, wr, wa);
  k_phase1<<<gq, 256, 0, stream>>>(ent16, rel16, attr16, eaw, caw,
                                   er_idx, ea_idx, ee, per, pea, pee, wr, wa,
                                   UA0, VB0, UA1, VB1, out, x16a);
  // layer 0
  k_se<<<nb, 256, 0, stream>>>(ee, er_rel2, UA0, VB0, HH0, eab, cab, s01, partials);
  k_final<<<1, 1024, 0, stream>>>(partials, scal, nb);
  k_q<<<nb, 256, 0, stream>>>(s01, scal);
  k_agg<<<gq, 256, 0, stream>>>(ee, pee, s01, x16a, out, 0,
                                eaw + 2 * 192, UA1, VB1, x16b);
  // layer 1
  k_se<<<nb, 256, 0, stream>>>(ee, er_rel2, UA1, VB1, HH1, eab + 2, cab + 2, s01, partials);
  k_final<<<1, 1024, 0, stream>>>(partials, scal, nb);
  k_q<<<nb, 256, 0, stream>>>(s01, scal);
  k_agg<<<gq, 256, 0, stream>>>(ee, pee, s01, x16b, out, 128,
                                (const float*)nullptr, (float4*)nullptr, (float4*)nullptr,
                                (unsigned*)nullptr);
}

// Round 10
// 208.821 us; speedup vs baseline: 1.2552x; 1.2552x over previous
//
#include <hip/hip_runtime.h>
#include <math.h>

#define NENT 50000
#define RREL 2000
#define AATT 5000
#define EE   400000
#define E2   800000
#define EAE  400000
#define PB   2048   // partials stride per head

__device__ __forceinline__ float leaky(float v){ return v > 0.f ? v : 0.3f * v; }

__device__ __forceinline__ float wave_sum(float v){
#pragma unroll
  for (int m = 32; m; m >>= 1) v += __shfl_xor(v, m);
  return v;
}
__device__ __forceinline__ float sum16(float v){
#pragma unroll
  for (int m = 1; m < 16; m <<= 1) v += __shfl_xor(v, m);
  return v;
}
__device__ __forceinline__ float sum8(float v){
#pragma unroll
  for (int m = 1; m < 8; m <<= 1) v += __shfl_xor(v, m);
  return v;
}

__device__ int lowb(const int* a, int n, int key){
  int lo = 0, hi = n;
  while (lo < hi){ int mid = (lo + hi) >> 1; if (a[2 * mid] < key) lo = mid + 1; else hi = mid; }
  return lo;
}

__global__ void k_ptr(const int* ee, const int* er, const int* ea,
                      int* pee, int* per, int* pea){
  int i = blockIdx.x * blockDim.x + threadIdx.x;
  if (i > NENT) return;
  pee[i] = lowb(ee, EE, i);
  per[i] = lowb(er, E2, i);
  pea[i] = lowb(ea, EAE, i);
}

// per-relation/attr scalar tables; HH_l[r] = (hr_h0, hr_h1, hc_h0, hc_h1)
__global__ void k_small(const float* rel_emb, const float* attr_emb,
                        const float* w_r, const float* w_a,
                        const float* eaw, const float* caw,
                        float* h_rel, float* h_attr, float4* HH0, float4* HH1){
  int t = blockIdx.x * blockDim.x + threadIdx.x;
  if (t < RREL){
    const float* e = rel_emb + (size_t)t * 64;
    float s = 0.f;
    for (int k = 0; k < 64; ++k) s += e[k] * w_r[128 + k];
    h_rel[t] = s;
    float hr[4], hc[4];
    for (int lh = 0; lh < 4; ++lh){
      float a = 0.f, c = 0.f;
      for (int k = 0; k < 64; ++k){
        a += e[k] * eaw[lh * 192 + 64 + k];
        c += e[k] * caw[lh * 320 + 128 + k];
      }
      hr[lh] = a; hc[lh] = c;
    }
    HH0[t] = make_float4(hr[0], hr[1], hc[0], hc[1]);
    HH1[t] = make_float4(hr[2], hr[3], hc[2], hc[3]);
  }
  if (t < AATT){
    const float* e = attr_emb + (size_t)t * 64;
    float s = 0.f;
    for (int k = 0; k < 64; ++k) s += e[k] * w_a[128 + k];
    h_attr[t] = s;
  }
}

// per-entity dot(ent_emb_row, w[:128]) tables; wave per entity
__global__ void k_ent_tab(const float* ent_emb, const float* w_r, const float* w_a,
                          float* her, float* hea){
  int w = (blockIdx.x * blockDim.x + threadIdx.x) >> 6;
  int lane = threadIdx.x & 63;
  if (w >= NENT) return;
  float2 v = ((const float2*)(ent_emb + (size_t)w * 128))[lane];
  float2 a = ((const float2*)w_r)[lane];
  float2 b = ((const float2*)w_a)[lane];
  float sr = wave_sum(v.x * a.x + v.y * a.y);
  float sa = wave_sum(v.x * b.x + v.y * b.y);
  if (lane == 0){ her[w] = sr; hea[w] = sa; }
}

// edge-parallel concept-attention weights for BOTH lists
__global__ void k_cw(const int* er_idx, const int* ea_idx,
                     const float* her, const float* hea,
                     const float* h_rel, const float* h_attr,
                     const float* b_r, const float* b_a,
                     float* wr, float* wa){
  int e = blockIdx.x * blockDim.x + threadIdx.x;
  if (e < E2){
    int2 rc = ((const int2*)er_idx)[e];
    wr[e] = __expf(leaky(her[rc.x] + h_rel[rc.y] + b_r[0]));
  }
  if (e < EAE){
    int2 rc = ((const int2*)ea_idx)[e];
    wa[e] = __expf(leaky(hea[rc.x] + h_attr[rc.y] + b_a[0]));
  }
}

// concept aggregation with precomputed weights. 16-lane group per entity.
// Pass1: seg-sum of wq (lane-strided). Pass2: unroll-8, clamp-to-chunk-start
// (duplicate loads hit L1), weight zeroed by cndmask. No shfl/exp in loops.
__device__ float4 concept_g(const float* wq, const int* idx, int beg, int end,
                            const float* emb, int p){
  float t = 0.f;
  for (int e = beg + p; e < end; e += 16) t += wq[e];
  t = sum16(t);
  float invz = (t > 0.f) ? (1.f / t) : 0.f;
  float4 acc = {0.f, 0.f, 0.f, 0.f};
  for (int c0 = beg; c0 < end; c0 += 8){
    int cnt = end - c0; if (cnt > 8) cnt = 8;
#pragma unroll
    for (int j = 0; j < 8; ++j){
      int e = c0 + ((j < cnt) ? j : 0);
      float wgt = wq[e] * invz;
      if (j >= cnt) wgt = 0.f;
      int obj = ((const int2*)idx)[e].y;
      float4 f = ((const float4*)(emb + (size_t)obj * 64))[p];
      acc.x = fmaf(wgt, f.x, acc.x); acc.y = fmaf(wgt, f.y, acc.y);
      acc.z = fmaf(wgt, f.z, acc.z); acc.w = fmaf(wgt, f.w, acc.w);
    }
  }
  acc.x = fmaxf(acc.x, 0.f); acc.y = fmaxf(acc.y, 0.f);
  acc.z = fmaxf(acc.z, 0.f); acc.w = fmaxf(acc.w, 0.f);
  return acc;
}

// row-local per-entity work, 16-lane group per entity (4 entities/wave):
// both concept GATs (precomputed weights), mean aggregation, A/B tables, uv0.
__global__ void k_phase1(const float* ent_emb, const float* rel_emb, const float* attr_emb,
                         const float* eaw, const float* caw,
                         const int* er_idx, const int* ea_idx, const int* ee,
                         const int* per, const int* pea, const int* pee,
                         const float* wr, const float* wa,
                         float4* UA0, float4* VB0, float4* UA1, float4* VB1,
                         float* out){
  int tid = blockIdx.x * blockDim.x + threadIdx.x;
  int lane = threadIdx.x & 63;
  int p = lane & 15;
  int w = (tid >> 6) * 4 + (lane >> 4);
  if (w >= NENT) return;
  // concept aggregations (lane p owns dims [4p,4p+4))
  float4 accR = concept_g(wr, er_idx, per[w], per[w + 1], rel_emb, p);
  float4 accA = concept_g(wa, ea_idx, pea[w], pea[w + 1], attr_emb, p);
  ((float4*)(out + (size_t)w * 384 + 256))[p] = accR;
  ((float4*)(out + (size_t)w * 384 + 320))[p] = accA;
  ((float4*)(out + (size_t)NENT * 384 + (size_t)w * 128))[p] = accR;
  ((float4*)(out + (size_t)NENT * 384 + (size_t)w * 128 + 64))[p] = accA;
  // mean neighbor aggregation (512 B ent rows), unroll-8 with clamp
  int beg = pee[w], end = pee[w + 1];
  float4 mx = {0.f,0.f,0.f,0.f}, my = {0.f,0.f,0.f,0.f};
  for (int c0 = beg; c0 < end; c0 += 8){
    int cnt = end - c0; if (cnt > 8) cnt = 8;
#pragma unroll
    for (int j = 0; j < 8; ++j){
      int e = c0 + ((j < cnt) ? j : 0);
      float msk = (j < cnt) ? 1.f : 0.f;
      int ce = ((const int2*)ee)[e].y;
      const float4* r = (const float4*)(ent_emb + (size_t)ce * 128);
      float4 q0 = r[2 * p], q1 = r[2 * p + 1];
      mx.x = fmaf(msk, q0.x, mx.x); mx.y = fmaf(msk, q0.y, mx.y);
      mx.z = fmaf(msk, q0.z, mx.z); mx.w = fmaf(msk, q0.w, mx.w);
      my.x = fmaf(msk, q1.x, my.x); my.y = fmaf(msk, q1.y, my.y);
      my.z = fmaf(msk, q1.z, my.z); my.w = fmaf(msk, q1.w, my.w);
    }
  }
  float invd = 1.f / fmaxf((float)(end - beg), 1.f);
  mx.x *= invd; mx.y *= invd; mx.z *= invd; mx.w *= invd;
  my.x *= invd; my.y *= invd; my.z *= invd; my.w *= invd;
  ((float4*)(out + (size_t)w * 384 + 128))[2 * p]     = mx;
  ((float4*)(out + (size_t)w * 384 + 128))[2 * p + 1] = my;
  // con-attention tables A (row) / B (col) for all 4 (l,h)
#pragma unroll
  for (int lh = 0; lh < 4; ++lh){
    const float* cw = caw + lh * 320;
    float4 c0 = *(const float4*)(cw + 4 * p);
    float4 c1 = *(const float4*)(cw + 64 + 4 * p);
    float4 c2 = *(const float4*)(cw + 192 + 4 * p);
    float4 c3 = *(const float4*)(cw + 256 + 4 * p);
    float av = accR.x*c0.x + accR.y*c0.y + accR.z*c0.z + accR.w*c0.w
             + accA.x*c1.x + accA.y*c1.y + accA.z*c1.z + accA.w*c1.w;
    float bv = accR.x*c2.x + accR.y*c2.y + accR.z*c2.z + accR.w*c2.w
             + accA.x*c3.x + accA.y*c3.y + accA.z*c3.z + accA.w*c3.w;
    av = sum16(av); bv = sum16(bv);
    if (p == 0){
      float4* U = (lh < 2) ? UA0 : UA1;
      float4* V = (lh < 2) ? VB0 : VB1;
      ((float*)(U + w))[2 + (lh & 1)] = av;
      ((float*)(V + w))[2 + (lh & 1)] = bv;
    }
  }
  // layer-0 u/v from x0: lane p owns dims [8p,8p+8); p<8 head0, p>=8 head1
  {
    int hh = p >> 3;
    int dbase = (8 * p) & 63;
    const float* wvp = eaw + hh * 192;
    float4 u0 = *(const float4*)(wvp + dbase);
    float4 u1 = *(const float4*)(wvp + dbase + 4);
    float4 q0 = *(const float4*)(wvp + 128 + dbase);
    float4 q1 = *(const float4*)(wvp + 128 + dbase + 4);
    float e0 = fmaxf(mx.x,0.f), e1 = fmaxf(mx.y,0.f), e2 = fmaxf(mx.z,0.f), e3 = fmaxf(mx.w,0.f);
    float e4 = fmaxf(my.x,0.f), e5 = fmaxf(my.y,0.f), e6 = fmaxf(my.z,0.f), e7 = fmaxf(my.w,0.f);
    float pu = e0*u0.x + e1*u0.y + e2*u0.z + e3*u0.w
             + e4*u1.x + e5*u1.y + e6*u1.z + e7*u1.w;
    float pv = e0*q0.x + e1*q0.y + e2*q0.z + e3*q0.w
             + e4*q1.x + e5*q1.y + e6*q1.z + e7*q1.w;
    pu = sum8(pu); pv = sum8(pv);
    if (p == 0 || p == 8){
      ((float*)(UA0 + w))[hh] = pu;
      ((float*)(VB0 + w))[hh] = pv;
    }
  }
}

// fused edge scores + exp (no global max) + block sums; s01[e] = {ex0, ex1}
__global__ void k_se(const int* ee, const int* err,
                     const float4* UA, const float4* VB, const float4* HH,
                     const float* eab_l, const float* cab_l,
                     float2* s01, float* partials){
  int e = blockIdx.x * blockDim.x + threadIdx.x;
  int tid = threadIdx.x;
  __shared__ float sm0[4], sm1[4];
  float ex0 = 0.f, ex1 = 0.f;
  if (e < EE){
    int2 rc = ((const int2*)ee)[e];
    int2 rr = ((const int2*)err)[e];
    float4 ua = UA[rc.x], vb = VB[rc.y], h1 = HH[rr.x], h2 = HH[rr.y];
    float ea0 = ua.x + 0.5f * (h1.x + h2.x) + vb.x + eab_l[0];
    float ca0 = ua.z + 0.5f * (h1.z + h2.z) + vb.z + cab_l[0];
    ex0 = __expf(leaky(ea0) * leaky(ca0));
    float ea1 = ua.y + 0.5f * (h1.y + h2.y) + vb.y + eab_l[1];
    float ca1 = ua.w + 0.5f * (h1.w + h2.w) + vb.w + cab_l[1];
    ex1 = __expf(leaky(ea1) * leaky(ca1));
    s01[e] = make_float2(ex0, ex1);
  }
  float b0 = wave_sum(ex0), b1 = wave_sum(ex1);
  if ((tid & 63) == 0){ sm0[tid >> 6] = b0; sm1[tid >> 6] = b1; }
  __syncthreads();
  if (tid == 0)  partials[blockIdx.x]      = sm0[0] + sm0[1] + sm0[2] + sm0[3];
  if (tid == 64) partials[PB + blockIdx.x] = sm1[0] + sm1[1] + sm1[2] + sm1[3];
}

// single-block finalize: Z per head
__global__ void k_final(const float* partials, float* scal, int nb){
  __shared__ float sm[1024];
  int tid = threadIdx.x;
  for (int h = 0; h < 2; ++h){
    float v = 0.f;
    for (int i = tid; i < nb; i += 1024) v += partials[h * PB + i];
    sm[tid] = v; __syncthreads();
    for (int s = 512; s; s >>= 1){
      if (tid < s) sm[tid] += sm[tid + s];
      __syncthreads();
    }
    if (tid == 0) scal[h] = sm[0];
    __syncthreads();
  }
}

// SINGLE-PASS segment softmax + PV via linearization: p = s/Z is tiny
// (<=~1e-3), so exp(p) = 1+p to ~5e-7 relative. Weight = (1+p_e)/(cnt+sum p).
// out = tanh((Sum x + invZ*Sum s*x)/(cnt + invZ*T)). Each lane accumulates all
// edges of its group's segment (clamp-dup + mask), so T is lane-replicated —
// no cross-lane reduce at all. lane p owns dims [8p,8p+8); p<8 h0, p>=8 h1.
__global__ void k_agg(const int* ee, const int* ptr, const float2* q01,
                      const float* scal, const float* xsrc, float* outp, int ocol,
                      const float* eaw_next, float4* UAn, float4* VBn){
  int tid = blockIdx.x * blockDim.x + threadIdx.x;
  int lane = threadIdx.x & 63;
  int p = lane & 15;
  int w = (tid >> 6) * 4 + (lane >> 4);
  if (w >= NENT) return;
  int beg = ptr[w], end = ptr[w + 1];
  float invZ = (p < 8) ? (1.f / scal[0]) : (1.f / scal[1]);
  float4 a0 = {0.f,0.f,0.f,0.f}, a1 = {0.f,0.f,0.f,0.f};  // Sum s*x
  float4 b0 = {0.f,0.f,0.f,0.f}, b1 = {0.f,0.f,0.f,0.f};  // Sum x
  float T = 0.f;                                          // Sum s (own head)
  for (int c0 = beg; c0 < end; c0 += 8){
    int cnt = end - c0; if (cnt > 8) cnt = 8;
#pragma unroll
    for (int j = 0; j < 8; ++j){
      int e = c0 + ((j < cnt) ? j : 0);
      float2 q = q01[e];
      float s = (p < 8) ? q.x : q.y;
      if (j >= cnt) s = 0.f;
      float msk = (j < cnt) ? 1.f : 0.f;
      T += s;
      int cj = ((const int2*)ee)[e].y;
      const float4* r = (const float4*)(xsrc + (size_t)cj * 384);
      float4 f0 = r[2 * p], f1 = r[2 * p + 1];
      f0.x = fmaxf(f0.x, 0.f); f0.y = fmaxf(f0.y, 0.f);
      f0.z = fmaxf(f0.z, 0.f); f0.w = fmaxf(f0.w, 0.f);
      f1.x = fmaxf(f1.x, 0.f); f1.y = fmaxf(f1.y, 0.f);
      f1.z = fmaxf(f1.z, 0.f); f1.w = fmaxf(f1.w, 0.f);
      b0.x = fmaf(msk, f0.x, b0.x); b0.y = fmaf(msk, f0.y, b0.y);
      b0.z = fmaf(msk, f0.z, b0.z); b0.w = fmaf(msk, f0.w, b0.w);
      b1.x = fmaf(msk, f1.x, b1.x); b1.y = fmaf(msk, f1.y, b1.y);
      b1.z = fmaf(msk, f1.z, b1.z); b1.w = fmaf(msk, f1.w, b1.w);
      a0.x = fmaf(s, f0.x, a0.x); a0.y = fmaf(s, f0.y, a0.y);
      a0.z = fmaf(s, f0.z, a0.z); a0.w = fmaf(s, f0.w, a0.w);
      a1.x = fmaf(s, f1.x, a1.x); a1.y = fmaf(s, f1.y, a1.y);
      a1.z = fmaf(s, f1.z, a1.z); a1.w = fmaf(s, f1.w, a1.w);
    }
  }
  float cnt = (float)(end - beg);
  float denom = cnt + invZ * T;
  float inv = (end > beg) ? (1.f / denom) : 0.f;
  float4 o0, o1;
  o0.x = tanhf((b0.x + invZ * a0.x) * inv); o0.y = tanhf((b0.y + invZ * a0.y) * inv);
  o0.z = tanhf((b0.z + invZ * a0.z) * inv); o0.w = tanhf((b0.w + invZ * a0.w) * inv);
  o1.x = tanhf((b1.x + invZ * a1.x) * inv); o1.y = tanhf((b1.y + invZ * a1.y) * inv);
  o1.z = tanhf((b1.z + invZ * a1.z) * inv); o1.w = tanhf((b1.w + invZ * a1.w) * inv);
  ((float4*)(outp + (size_t)w * 384 + ocol))[2 * p]     = o0;
  ((float4*)(outp + (size_t)w * 384 + ocol))[2 * p + 1] = o1;
  if (eaw_next){
    int hh = p >> 3;
    int dbase = (8 * p) & 63;
    const float* wvp = eaw_next + hh * 192;
    float4 u0 = *(const float4*)(wvp + dbase);
    float4 u1 = *(const float4*)(wvp + dbase + 4);
    float4 q0 = *(const float4*)(wvp + 128 + dbase);
    float4 q1 = *(const float4*)(wvp + 128 + dbase + 4);
    float e0 = fmaxf(o0.x,0.f), e1 = fmaxf(o0.y,0.f), e2 = fmaxf(o0.z,0.f), e3 = fmaxf(o0.w,0.f);
    float e4 = fmaxf(o1.x,0.f), e5 = fmaxf(o1.y,0.f), e6 = fmaxf(o1.z,0.f), e7 = fmaxf(o1.w,0.f);
    float pu = e0*u0.x + e1*u0.y + e2*u0.z + e3*u0.w
             + e4*u1.x + e5*u1.y + e6*u1.z + e7*u1.w;
    float pv = e0*q0.x + e1*q0.y + e2*q0.z + e3*q0.w
             + e4*q1.x + e5*q1.y + e6*q1.z + e7*q1.w;
    pu = sum8(pu); pv = sum8(pv);
    if (p == 0 || p == 8){
      ((float*)(UAn + w))[hh] = pu;
      ((float*)(VBn + w))[hh] = pv;
    }
  }
}

extern "C" void kernel_launch(void* const* d_in, const int* in_sizes, int n_in,
                              void* d_out, int out_size, void* d_ws, size_t ws_size,
                              hipStream_t stream){
  const float* ent_emb  = (const float*)d_in[0];
  const float* rel_emb  = (const float*)d_in[1];
  const float* attr_emb = (const float*)d_in[2];
  const float* w_r      = (const float*)d_in[3];
  const float* b_r      = (const float*)d_in[4];
  const float* w_a      = (const float*)d_in[5];
  const float* b_a      = (const float*)d_in[6];
  const float* eaw      = (const float*)d_in[7];
  const float* eab      = (const float*)d_in[8];
  const float* caw      = (const float*)d_in[9];
  const float* cab      = (const float*)d_in[10];
  const int*   ee       = (const int*)d_in[11];
  const int*   er_rel2  = (const int*)d_in[13];  // per-ee-edge relation pair (E2)
  const int*   er_idx   = (const int*)d_in[14];
  const int*   ea_idx   = (const int*)d_in[15];
  float* out = (float*)d_out;

  // workspace carve (~10 MB)
  int* pee = (int*)d_ws;                 // NENT+1
  int* per = pee + (NENT + 1);
  int* pea = per + (NENT + 1);
  float*  fbase = (float*)d_ws + 150004; // 16B-aligned
  float4* UA0 = (float4*)fbase;          // NENT each
  float4* VB0 = UA0 + NENT;
  float4* UA1 = VB0 + NENT;
  float4* VB1 = UA1 + NENT;
  float4* HH0 = VB1 + NENT;              // RREL each
  float4* HH1 = HH0 + RREL;
  float* her     = (float*)(HH1 + RREL); // NENT
  float* hea     = her + NENT;           // NENT
  float* h_rel   = hea + NENT;           // RREL
  float* h_attr  = h_rel + RREL;         // AATT
  float* partials= h_attr + AATT;        // 2*PB
  float* scal    = partials + 2 * PB;    // 4
  float* wr      = scal + 4;             // E2 floats; ALIASED with s01 (EE float2)
  float* wa      = wr + E2;              // EAE floats
  float2* s01    = (float2*)wr;          // wr dead after k_phase1

  const int nb = (EE + 255) / 256;       // 1563 edge blocks
  const int gq = (NENT + 15) / 16;       // group-per-entity grids (16 ent/block)
  const int gw = (NENT + 3) / 4;         // wave-per-entity grids

  k_ptr<<<(NENT + 1 + 255) / 256, 256, 0, stream>>>(ee, er_idx, ea_idx, pee, per, pea);
  k_small<<<(AATT + 255) / 256, 256, 0, stream>>>(rel_emb, attr_emb, w_r, w_a, eaw, caw,
                                                  h_rel, h_attr, HH0, HH1);
  k_ent_tab<<<gw, 256, 0, stream>>>(ent_emb, w_r, w_a, her, hea);
  k_cw<<<(E2 + 255) / 256, 256, 0, stream>>>(er_idx, ea_idx, her, hea,
                                             h_rel, h_attr, b_r, b_a, wr, wa);
  k_phase1<<<gq, 256, 0, stream>>>(ent_emb, rel_emb, attr_emb, eaw, caw,
                                   er_idx, ea_idx, ee, per, pea, pee, wr, wa,
                                   UA0, VB0, UA1, VB1, out);
  // layer 0
  k_se<<<nb, 256, 0, stream>>>(ee, er_rel2, UA0, VB0, HH0, eab, cab, s01, partials);
  k_final<<<1, 1024, 0, stream>>>(partials, scal, nb);
  k_agg<<<gq, 256, 0, stream>>>(ee, pee, s01, scal, out + 128, out, 0,
                                eaw + 2 * 192, UA1, VB1);
  // layer 1
  k_se<<<nb, 256, 0, stream>>>(ee, er_rel2, UA1, VB1, HH1, eab + 2, cab + 2, s01, partials);
  k_final<<<1, 1024, 0, stream>>>(partials, scal, nb);
  k_agg<<<gq, 256, 0, stream>>>(ee, pee, s01, scal, out, out, 128,
                                (const float*)nullptr, (float4*)nullptr, (float4*)nullptr);
}